// Round 14
// baseline (990.583 us; speedup 1.0000x reference)
//
#include <hip/hip_runtime.h>
#include <math.h>

#define NP 256
#define HID 512
#define KB 8        // LU panel width
#define BT2 32      // b rows per MLP block
#define PH_C 256    // c staged per phase
#define H0P 36      // h0s row stride: 4*36 % 32 == 16 -> 2-way (free) on A-reads

typedef short bf16x8 __attribute__((ext_vector_type(8)));
typedef float f32x4v __attribute__((ext_vector_type(4)));

// RNE bf16 with exact residual (v - bf16(v) is exactly representable).
__device__ __forceinline__ short bf16_rne(float v, float& rem) {
    unsigned u = __float_as_uint(v);
    unsigned r = (u + 0x7FFFu + ((u >> 16) & 1u)) & 0xFFFF0000u;
    rem = v - __uint_as_float(r);
    return (short)(r >> 16);
}
// 3-way RNE split: v = h + m + lo + r3, |r3| <= 2^-27 |v| (unbiased).
__device__ __forceinline__ void split3(float v, short& h, short& m, short& lo) {
    float r1, r2;
    h = bf16_rne(v, r1);
    m = bf16_rne(r1, r2);
    unsigned u2 = __float_as_uint(r2);
    lo = (short)((u2 + 0x7FFFu + ((u2 >> 16) & 1u)) >> 16);
}

// MFMA MLP, layer-1 on matrix cores via RNE 3-way bf16 split (6 products).
// Grid (bt, w): blocks sharing W1[w] are dispatched consecutively -> L2
// reuse, W1 fetched ~once (round-13 grid (w,bt) streamed W1 up to 8x:
// FETCH 715 MB, HBM-bound). Fragment maps validated in round 13.
__global__ __launch_bounds__(256) void k_mlp_mfma(
    const float* __restrict__ x,  const float* __restrict__ W0,
    const float* __restrict__ b0, const float* __restrict__ W1,
    const float* __restrict__ b1, const float* __restrict__ W2,
    const float* __restrict__ b2, float* __restrict__ slater)
{
    __shared__ float h0s[PH_C][H0P];   // 36.9 KB
    __shared__ float s_red[4][BT2];
    const int w   = blockIdx.y;
    const int bt0 = blockIdx.x * BT2;
    const int tid = threadIdx.x;
    const int wid = tid >> 6;      // wave 0..3 -> f-range wid*128
    const int l   = tid & 63;
    const int col = l & 15;
    const int g   = l >> 4;        // lane group 0..3

    f32x4v acc[2][8];
    #pragma unroll
    for (int bt = 0; bt < 2; ++bt)
        #pragma unroll
        for (int ft = 0; ft < 8; ++ft)
            acc[bt][ft] = (f32x4v){0.f, 0.f, 0.f, 0.f};

    // layer-0 thread mapping
    const int b0i = tid & 31;
    const int co  = tid >> 5;      // 0..7
    const int bg  = bt0 + b0i;
    const float x0 = x[bg*3+0], x1 = x[bg*3+1], x2 = x[bg*3+2];
    const float* W0w = W0 + (size_t)w*3*HID;
    const float* b0w = b0 + (size_t)w*HID;
    const float* w1w = W1 + (size_t)w*HID*HID + wid*128 + col;

    for (int ph = 0; ph < 2; ++ph) {
        if (ph) __syncthreads();
        // ---- layer 0: h0s[cl][b] = tanh(x[b,:]@W0[w,:,c] + b0[w,c]) ----
        #pragma unroll 4
        for (int pass = 0; pass < 32; ++pass) {
            int cl = co + 8*pass;
            int c  = ph*PH_C + cl;
            float v = x0*W0w[c] + x1*W0w[HID+c] + x2*W0w[2*HID+c] + b0w[c];
            h0s[cl][b0i] = tanhf(v);
        }
        __syncthreads();

        // ---- layer 1: 8 K-steps of 32 per phase, MFMA 3-split ----
        for (int ks = 0; ks < 8; ++ks) {
            const int k0 = ks*32;
            bf16x8 Ah[2], Am[2], Al[2];
            #pragma unroll
            for (int bt = 0; bt < 2; ++bt)
                #pragma unroll
                for (int j = 0; j < 8; ++j) {
                    int k = 4*g + (j&3) + 16*(j>>2);
                    float v = h0s[k0 + k][bt*16 + col];
                    short h, m, lo; split3(v, h, m, lo);
                    Ah[bt][j] = h; Am[bt][j] = m; Al[bt][j] = lo;
                }
            const float* bp = w1w + (size_t)(ph*PH_C + k0 + 4*g)*HID;
            #pragma unroll
            for (int ft = 0; ft < 8; ++ft) {
                bf16x8 Bh, Bm, Bl;
                #pragma unroll
                for (int j = 0; j < 8; ++j) {
                    int koff = (j&3) + 16*(j>>2);
                    float v = bp[(size_t)koff*HID + ft*16];
                    short h, m, lo; split3(v, h, m, lo);
                    Bh[j] = h; Bm[j] = m; Bl[j] = lo;
                }
                #pragma unroll
                for (int bt = 0; bt < 2; ++bt) {
                    acc[bt][ft] = __builtin_amdgcn_mfma_f32_16x16x32_bf16(Ah[bt], Bh, acc[bt][ft], 0,0,0);
                    acc[bt][ft] = __builtin_amdgcn_mfma_f32_16x16x32_bf16(Ah[bt], Bm, acc[bt][ft], 0,0,0);
                    acc[bt][ft] = __builtin_amdgcn_mfma_f32_16x16x32_bf16(Am[bt], Bh, acc[bt][ft], 0,0,0);
                    acc[bt][ft] = __builtin_amdgcn_mfma_f32_16x16x32_bf16(Ah[bt], Bl, acc[bt][ft], 0,0,0);
                    acc[bt][ft] = __builtin_amdgcn_mfma_f32_16x16x32_bf16(Am[bt], Bm, acc[bt][ft], 0,0,0);
                    acc[bt][ft] = __builtin_amdgcn_mfma_f32_16x16x32_bf16(Al[bt], Bh, acc[bt][ft], 0,0,0);
                }
            }
        }
    }

    // ---- epilogue: tanh(acc+b1).W2, reduce over f, write slater row ----
    const float* b1w = b1 + (size_t)w*HID + wid*128;
    const float* W2w = W2 + (size_t)w*HID + wid*128;
    float bb[8], wt[8];
    #pragma unroll
    for (int ft = 0; ft < 8; ++ft) {
        bb[ft] = b1w[ft*16 + col];
        wt[ft] = W2w[ft*16 + col];
    }
    #pragma unroll
    for (int bt = 0; bt < 2; ++bt)
        #pragma unroll
        for (int r = 0; r < 4; ++r) {
            float part = 0.f;
            #pragma unroll
            for (int ft = 0; ft < 8; ++ft)
                part += tanhf(acc[bt][ft][r] + bb[ft]) * wt[ft];
            part += __shfl_xor(part, 1); part += __shfl_xor(part, 2);
            part += __shfl_xor(part, 4); part += __shfl_xor(part, 8);
            if (col == 0) s_red[wid][bt*16 + 4*g + r] = part;
        }
    __syncthreads();
    if (tid < BT2)
        slater[w*NP + bt0 + tid] = s_red[0][tid] + s_red[1][tid]
                                 + s_red[2][tid] + s_red[3][tid] + b2[w];
}

__device__ __forceinline__ float rf_f32(float x) {
    return __uint_as_float(__builtin_amdgcn_readfirstlane(__float_as_uint(x)));
}
__device__ __forceinline__ float rl_f32(float x, int lane) {
    return __uint_as_float(__builtin_amdgcn_readlane(__float_as_uint(x), lane));
}
template<int CTRL>
__device__ __forceinline__ unsigned dpp_u32(unsigned v) {
    return (unsigned)__builtin_amdgcn_update_dpp(0, (int)v, CTRL, 0xF, 0xF, true);
}

// Blocked (KB=8) partially-pivoted f32 LU, matrix register-resident.
// Byte-identical to the passing round-11/12/13 version.
__global__ __launch_bounds__(512, 1) void k_lu_blk(const float* __restrict__ A,
                                                   float* __restrict__ out)
{
    const int tid  = threadIdx.x;
    const int ln   = tid & 63;      // lane: row-in-quarter
    const int wv   = tid >> 6;      // wave id = 32-col slice (wave-uniform)
    const int cb   = wv * 32;       // col base

    __shared__ float s_panel[NP][KB+1];   // stride 9: conflict-free scalar access
    __shared__ float s_stage[2*KB][260];  // staged rows (full 256 cols + pad)
    __shared__ float s_U[KB][260];        // TRSM'd U block
    __shared__ int   s_src[NP];
    __shared__ int   s_p[KB];
    __shared__ int   s_uslot[KB];
    __shared__ float s_piv[NP];

    float a[4][32];                       // rows q*64+ln, cols cb..cb+31
    {
        const float4* Ap = reinterpret_cast<const float4*>(A);
        #pragma unroll
        for (int q = 0; q < 4; ++q)
            #pragma unroll
            for (int u = 0; u < 8; ++u) {
                float4 v = Ap[(q*64+ln)*64 + wv*8 + u];
                a[q][u*4+0]=v.x; a[q][u*4+1]=v.y; a[q][u*4+2]=v.z; a[q][u*4+3]=v.w;
            }
    }

    for (int pi = 0; pi < NP/KB; ++pi) {
        const int k0 = pi * KB;
        __syncthreads();                                  // B0

        // ---- STEP 1: stage panel cols + init s_src ----
        if (tid < 256) s_src[tid] = tid;
        if (wv == (k0 >> 5)) {                            // wave-uniform
            switch ((k0 & 31) >> 3) {
                case 0:
                    #pragma unroll
                    for (int q = 0; q < 4; ++q)
                        #pragma unroll
                        for (int c = 0; c < KB; ++c) s_panel[q*64+ln][c] = a[q][c];
                    break;
                case 1:
                    #pragma unroll
                    for (int q = 0; q < 4; ++q)
                        #pragma unroll
                        for (int c = 0; c < KB; ++c) s_panel[q*64+ln][c] = a[q][8+c];
                    break;
                case 2:
                    #pragma unroll
                    for (int q = 0; q < 4; ++q)
                        #pragma unroll
                        for (int c = 0; c < KB; ++c) s_panel[q*64+ln][c] = a[q][16+c];
                    break;
                default:
                    #pragma unroll
                    for (int q = 0; q < 4; ++q)
                        #pragma unroll
                        for (int c = 0; c < KB; ++c) s_panel[q*64+ln][c] = a[q][24+c];
                    break;
            }
        }
        __syncthreads();                                  // B1

        // ---- STEP 2: wave 0 factorizes the 256x8 panel (LDS-free core) ----
        if (tid < 64) {
            const int lane = tid;
            float pa[4][KB];
            int   lid[4];                  // logical position of slot q's row
            #pragma unroll
            for (int q = 0; q < 4; ++q) {
                lid[q] = q*64 + lane;
                #pragma unroll
                for (int c = 0; c < KB; ++c) pa[q][c] = s_panel[q*64+lane][c];
            }

            int pvt[KB];
            #pragma unroll
            for (int kk = 0; kk < KB; ++kk) {
                const int k = k0 + kk;
                // packed-key candidates: top-24 bits of |v| | (255 - lid)
                unsigned key = 0u;
                #pragma unroll
                for (int q = 0; q < 4; ++q) {
                    unsigned ab = __float_as_uint(pa[q][kk]) & 0x7FFFFFFFu;
                    unsigned kq = (ab & 0xFFFFFF00u) | (unsigned)(255 - lid[q]);
                    if (lid[q] >= k && kq > key) key = kq;
                }
                // 6-step DPP max-reduce -> lane 63 holds global max
                { unsigned t;
                  t = dpp_u32<0x111>(key); if (t > key) key = t;   // row_shr:1
                  t = dpp_u32<0x112>(key); if (t > key) key = t;   // row_shr:2
                  t = dpp_u32<0x114>(key); if (t > key) key = t;   // row_shr:4
                  t = dpp_u32<0x118>(key); if (t > key) key = t;   // row_shr:8
                  t = dpp_u32<0x142>(key); if (t > key) key = t;   // row_bcast:15
                  t = dpp_u32<0x143>(key); if (t > key) key = t;   // row_bcast:31
                }
                const unsigned gk = (unsigned)__builtin_amdgcn_readlane((int)key, 63);
                const int p = 255 - (int)(gk & 0xFFu);   // logical pivot row
                pvt[kk] = p;
                // physical holder of logical row p: (plane, pslot)
                int myslot = -1;
                #pragma unroll
                for (int q = 0; q < 4; ++q) if (lid[q] == p) myslot = q;
                unsigned long long bal = __ballot(myslot >= 0);
                const int plane = (int)__ffsll((long long)bal) - 1;
                const int pslot = __builtin_amdgcn_readlane(myslot, plane);
                // pivot-row broadcast (KB independent readlanes)
                float urow[KB];
                #pragma unroll
                for (int c = 0; c < KB; ++c) {
                    float t = (pslot==0) ? pa[0][c] : (pslot==1) ? pa[1][c]
                            : (pslot==2) ? pa[2][c] : pa[3][c];
                    urow[c] = rl_f32(t, plane);
                }
                // lazy swap of logical ids
                #pragma unroll
                for (int q = 0; q < 4; ++q) {
                    int lq = lid[q];
                    lid[q] = (lq == k) ? p : (lq == p) ? k : lq;
                }
                const float pv = urow[kk];
                if (lane == 0) s_piv[k] = (p != k) ? -pv : pv;
                const float rp = rf_f32(1.0f / pv);
                #pragma unroll
                for (int q = 0; q < 4; ++q)
                    if (lid[q] > k) pa[q][kk] *= rp;
                #pragma unroll
                for (int c = kk+1; c < KB; ++c) {
                    #pragma unroll
                    for (int q = 0; q < 4; ++q)
                        if (lid[q] > k) pa[q][c] = fmaf(-pa[q][kk], urow[c], pa[q][c]);
                }
            }
            // write back factored panel BY LOGICAL INDEX + pivots
            #pragma unroll
            for (int q = 0; q < 4; ++q)
                #pragma unroll
                for (int c = 0; c < KB; ++c) s_panel[lid[q]][c] = pa[q][c];
            if (lane == 0) {
                s_p[0]=pvt[0]; s_p[1]=pvt[1]; s_p[2]=pvt[2]; s_p[3]=pvt[3];
                s_p[4]=pvt[4]; s_p[5]=pvt[5]; s_p[6]=pvt[6]; s_p[7]=pvt[7];
            }
            // in-register swap simulation on 16 tracked positions
            int l8 = lane - 8;
            int psel = pvt[0];
            psel = (l8==1)?pvt[1]:psel; psel = (l8==2)?pvt[2]:psel;
            psel = (l8==3)?pvt[3]:psel; psel = (l8==4)?pvt[4]:psel;
            psel = (l8==5)?pvt[5]:psel; psel = (l8==6)?pvt[6]:psel;
            psel = (l8==7)?pvt[7]:psel;
            const int mypos = (lane < 8) ? (k0 + lane) : psel;
            int cur = mypos;
            #pragma unroll
            for (int s = 0; s < KB; ++s) {
                int cA = __builtin_amdgcn_readlane(cur, s);     // content at k0+s
                int cB = __builtin_amdgcn_readlane(cur, 8+s);   // content at pvt[s]
                int ks = k0 + s, ps = pvt[s];
                if (mypos == ks) cur = cB;
                else if (mypos == ps) cur = cA;
            }
            if (lane < 16) s_src[mypos] = cur;
            if (lane < 8) {
                int c = cur, slot = 8;
                slot = (pvt[0]==c)? 8:slot; slot = (pvt[1]==c)? 9:slot;
                slot = (pvt[2]==c)?10:slot; slot = (pvt[3]==c)?11:slot;
                slot = (pvt[4]==c)?12:slot; slot = (pvt[5]==c)?13:slot;
                slot = (pvt[6]==c)?14:slot; slot = (pvt[7]==c)?15:slot;
                if (c >= k0 && c < k0+KB) slot = c - k0;
                s_uslot[lane] = slot;
            }
        }
        __syncthreads();                                  // B2

        int pp[KB];
        #pragma unroll
        for (int s = 0; s < KB; ++s) pp[s] = s_p[s];

        // ---- STEP 3: stage affected rows (pre-swap content, by position) ----
        #pragma unroll
        for (int q = 0; q < 4; ++q) {
            const int iq = q*64 + ln;
            if (iq >= k0 && iq < k0+KB) {
                const int sl = iq - k0;
                #pragma unroll
                for (int u = 0; u < 8; ++u) {
                    float4 v; v.x=a[q][u*4+0]; v.y=a[q][u*4+1];
                    v.z=a[q][u*4+2]; v.w=a[q][u*4+3];
                    *reinterpret_cast<float4*>(&s_stage[sl][cb + u*4]) = v;
                }
            }
            #pragma unroll
            for (int s = 0; s < KB; ++s) {
                if (iq == pp[s]) {
                    #pragma unroll
                    for (int u = 0; u < 8; ++u) {
                        float4 v; v.x=a[q][u*4+0]; v.y=a[q][u*4+1];
                        v.z=a[q][u*4+2]; v.w=a[q][u*4+3];
                        *reinterpret_cast<float4*>(&s_stage[KB+s][cb + u*4]) = v;
                    }
                }
            }
        }
        __syncthreads();                                  // B3

        // ---- STEP 4a: apply row permutation from stage ----
        #pragma unroll
        for (int q = 0; q < 4; ++q) {
            const int iq = q*64 + ln;
            const int sr = s_src[iq];
            if (sr != iq) {
                int slot = 8;
                #pragma unroll
                for (int s = 0; s < KB; ++s) slot = (pp[s]==sr) ? KB+s : slot;
                if (sr >= k0 && sr < k0+KB) slot = sr - k0;
                #pragma unroll
                for (int u = 0; u < 8; ++u) {
                    float4 v = *reinterpret_cast<const float4*>(&s_stage[slot][cb + u*4]);
                    a[q][u*4+0]=v.x; a[q][u*4+1]=v.y; a[q][u*4+2]=v.z; a[q][u*4+3]=v.w;
                }
            }
        }
        // ---- STEP 4b: TRSM of U block, column-parallel (tid<256, col j=tid) ----
        if (tid < 256) {
            const int j = tid;
            int us[KB];
            #pragma unroll
            for (int m = 0; m < KB; ++m) us[m] = s_uslot[m];
            float uv[KB];
            #pragma unroll
            for (int m = 0; m < KB; ++m) {
                float v = s_stage[us[m]][j];
                #pragma unroll
                for (int s = 0; s < KB; ++s)
                    if (s < m) v = fmaf(-s_panel[k0+m][s], uv[s], v);
                uv[m] = v;
                s_U[m][j] = v;
            }
        }
        __syncthreads();                                  // B4

        // ---- STEP 5: rank-8 trailing update (live col slices only;
        //      dead rows in straddling q-blocks updated inertly) ----
        if (cb + 31 >= k0 + KB) {                         // wave-uniform
            float L0[4][KB];
            #pragma unroll
            for (int q = 0; q < 4; ++q)
                #pragma unroll
                for (int m = 0; m < KB; ++m) L0[q][m] = s_panel[q*64+ln][m];
            #pragma unroll
            for (int u4 = 0; u4 < 8; ++u4) {
                if (cb + u4*4 + 3 >= k0 + KB) {           // wave-uniform
                    #pragma unroll
                    for (int m = 0; m < KB; ++m) {
                        const float4 uv = *reinterpret_cast<const float4*>(&s_U[m][cb + u4*4]);
                        #pragma unroll
                        for (int q = 0; q < 4; ++q) {
                            if (q*64 + 63 >= k0 + KB) {   // wave-uniform: block has live rows
                                a[q][u4*4+0] = fmaf(-L0[q][m], uv.x, a[q][u4*4+0]);
                                a[q][u4*4+1] = fmaf(-L0[q][m], uv.y, a[q][u4*4+1]);
                                a[q][u4*4+2] = fmaf(-L0[q][m], uv.z, a[q][u4*4+2]);
                                a[q][u4*4+3] = fmaf(-L0[q][m], uv.w, a[q][u4*4+3]);
                            }
                        }
                    }
                }
            }
        }
    }
    __syncthreads();

    // ---- logdet = sum log|piv| (f64 accum), sign = parity of negatives ----
    if (tid < 64) {
        double ld = 0.0; int neg = 0;
        #pragma unroll
        for (int q = 0; q < 4; ++q) {
            float pv = s_piv[q*64 + tid];
            ld  += (double)logf(fabsf(pv));
            neg ^= (pv < 0.0f) ? 1 : 0;
        }
        #pragma unroll
        for (int off = 32; off; off >>= 1) {
            ld  += __shfl_xor(ld, off);
            neg ^= __shfl_xor(neg, off);
        }
        if (tid == 0) { out[0] = neg ? -1.0f : 1.0f; out[1] = (float)ld; }
    }
}

extern "C" void kernel_launch(void* const* d_in, const int* in_sizes, int n_in,
                              void* d_out, int out_size, void* d_ws, size_t ws_size,
                              hipStream_t stream)
{
    const float* x  = (const float*)d_in[0];
    const float* W0 = (const float*)d_in[1];
    const float* b0 = (const float*)d_in[2];
    const float* W1 = (const float*)d_in[3];
    const float* b1 = (const float*)d_in[4];
    const float* W2 = (const float*)d_in[5];
    const float* b2 = (const float*)d_in[6];
    float* out    = (float*)d_out;
    float* slater = (float*)d_ws;           // 256*256*4 = 256 KB scratch

    // grid (bt, w): same-w blocks consecutive -> W1[w] L2 reuse
    k_mlp_mfma<<<dim3(NP/BT2, NP), 256, 0, stream>>>(x, W0, b0, W1, b1, W2, b2, slater);
    k_lu_blk<<<1, 512, 0, stream>>>(slater, out);
}

// Round 15
// 785.400 us; speedup vs baseline: 1.2612x; 1.2612x over previous
//
#include <hip/hip_runtime.h>
#include <math.h>

#define NP 256
#define HID 512
#define KB 8        // LU panel width

typedef short bf16x8 __attribute__((ext_vector_type(8)));
typedef float f32x4v __attribute__((ext_vector_type(4)));

// RNE bf16 with exact residual (v - bf16(v) is exactly representable).
__device__ __forceinline__ short bf16_rne(float v, float& rem) {
    unsigned u = __float_as_uint(v);
    unsigned r = (u + 0x7FFFu + ((u >> 16) & 1u)) & 0xFFFF0000u;
    rem = v - __uint_as_float(r);
    return (short)(r >> 16);
}
// 3-way RNE split: v = h + m + lo + r3, |r3| <= 2^-27 |v| (unbiased).
__device__ __forceinline__ void split3(float v, short& h, short& m, short& lo) {
    float r1, r2;
    h = bf16_rne(v, r1);
    m = bf16_rne(r1, r2);
    unsigned u2 = __float_as_uint(r2);
    lo = (short)((u2 + 0x7FFFu + ((u2 >> 16) & 1u)) >> 16);
}

// v3: BT=128, 512 threads, 2 blocks/w (B-split redundancy 8->2).
// h0 split ONCE at layer-0 into packed bf16 MFMA-A fragments in LDS
// (pA[mat][ks][g][row][j], 48 KB) shared by all 8 waves; A-frag load is one
// ds_read_b128. Grid decode puts the same-w block pair on the SAME XCD
// 8 bids apart -> W1 L2 reuse (r13: same XCD but 256 apart, 2.7x HBM;
// r14: adjacent but cross-XCD, 4x HBM). MFMA sequence per acc tile
// unchanged vs r14 -> absmax stays 64.0 (bf16-output quantized).
__global__ __launch_bounds__(512, 1) void k_mlp_v3(
    const float* __restrict__ x,  const float* __restrict__ W0,
    const float* __restrict__ b0, const float* __restrict__ W1,
    const float* __restrict__ b1, const float* __restrict__ W2,
    const float* __restrict__ b2, float* __restrict__ slater)
{
    __shared__ __align__(16) short pA[3][2][4][128][8];  // 48 KB
    __shared__ float s_red[8][128];                      // 4 KB
    const int bid  = blockIdx.x;
    const int xcd  = bid & 7;
    const int jj   = bid >> 3;
    const int half = jj & 1;
    const int w    = (xcd << 5) + (jj >> 1);
    const int tid  = threadIdx.x;
    const int wid  = tid >> 6;     // wave 0..7 -> f-slice wid*64
    const int l    = tid & 63;
    const int col  = l & 15;
    const int g    = l >> 4;
    const int fb   = wid * 64;

    f32x4v acc[8][4];
    #pragma unroll
    for (int bt = 0; bt < 8; ++bt)
        #pragma unroll
        for (int ft = 0; ft < 4; ++ft)
            acc[bt][ft] = (f32x4v){0.f, 0.f, 0.f, 0.f};

    // layer-0 mapping: 64 c x 128 b per phase, 16 per thread
    const int bb = tid & 127;
    const int co = tid >> 7;       // 0..3 (wave-pair uniform)
    const int bg = half*128 + bb;
    const float x0 = x[bg*3+0], x1 = x[bg*3+1], x2 = x[bg*3+2];
    const float* W0w = W0 + (size_t)w*3*HID;
    const float* b0w = b0 + (size_t)w*HID;
    const float* w1c = W1 + (size_t)w*HID*HID + fb + col;

    for (int ph = 0; ph < 8; ++ph) {
        if (ph) __syncthreads();
        // ---- layer 0: split h0 once into packed A-frags ----
        #pragma unroll 4
        for (int pass = 0; pass < 16; ++pass) {
            int cl = co + 4*pass;          // 0..63
            int c  = ph*64 + cl;
            float v = x0*W0w[c] + x1*W0w[HID+c] + x2*W0w[2*HID+c] + b0w[c];
            float t = tanhf(v);
            short h, m, lo; split3(t, h, m, lo);
            int ks = cl >> 5, r32 = cl & 31;
            int gg = (r32 >> 2) & 3;
            int jv = (r32 & 3) + 4*(r32 >> 4);
            pA[0][ks][gg][bb][jv] = h;
            pA[1][ks][gg][bb][jv] = m;
            pA[2][ks][gg][bb][jv] = lo;
        }
        __syncthreads();

        #pragma unroll
        for (int ks = 0; ks < 2; ++ks) {
            // ---- B: load f32 + split, all 4 ft (held live) ----
            bf16x8 Bh[4], Bm[4], Bl[4];
            const float* bkp = w1c + (size_t)(ph*64 + ks*32 + 4*g)*HID;
            #pragma unroll
            for (int ft = 0; ft < 4; ++ft)
                #pragma unroll
                for (int j = 0; j < 8; ++j) {
                    int koff = (j&3) + 16*(j>>2);
                    float v = bkp[(size_t)koff*HID + ft*16];
                    short h, m, lo; split3(v, h, m, lo);
                    Bh[ft][j] = h; Bm[ft][j] = m; Bl[ft][j] = lo;
                }
            // ---- A-frags in 2 chunks of 4 bt; 6-product MFMA ----
            #pragma unroll
            for (int btc = 0; btc < 2; ++btc) {
                bf16x8 Ah[4], Am[4], Al[4];
                #pragma unroll
                for (int b4 = 0; b4 < 4; ++b4) {
                    int row = (btc*4 + b4)*16 + col;
                    Ah[b4] = *reinterpret_cast<const bf16x8*>(&pA[0][ks][g][row][0]);
                    Am[b4] = *reinterpret_cast<const bf16x8*>(&pA[1][ks][g][row][0]);
                    Al[b4] = *reinterpret_cast<const bf16x8*>(&pA[2][ks][g][row][0]);
                }
                #pragma unroll
                for (int b4 = 0; b4 < 4; ++b4) {
                    const int bt = btc*4 + b4;
                    #pragma unroll
                    for (int ft = 0; ft < 4; ++ft) {
                        acc[bt][ft] = __builtin_amdgcn_mfma_f32_16x16x32_bf16(Ah[b4], Bh[ft], acc[bt][ft], 0,0,0);
                        acc[bt][ft] = __builtin_amdgcn_mfma_f32_16x16x32_bf16(Ah[b4], Bm[ft], acc[bt][ft], 0,0,0);
                        acc[bt][ft] = __builtin_amdgcn_mfma_f32_16x16x32_bf16(Am[b4], Bh[ft], acc[bt][ft], 0,0,0);
                        acc[bt][ft] = __builtin_amdgcn_mfma_f32_16x16x32_bf16(Ah[b4], Bl[ft], acc[bt][ft], 0,0,0);
                        acc[bt][ft] = __builtin_amdgcn_mfma_f32_16x16x32_bf16(Am[b4], Bm[ft], acc[bt][ft], 0,0,0);
                        acc[bt][ft] = __builtin_amdgcn_mfma_f32_16x16x32_bf16(Al[b4], Bh[ft], acc[bt][ft], 0,0,0);
                    }
                }
            }
        }
    }

    // ---- epilogue: tanh(acc+b1).W2, reduce over f, write slater row ----
    const float* b1w = b1 + (size_t)w*HID + fb;
    const float* W2w = W2 + (size_t)w*HID + fb;
    float bbv[4], wtv[4];
    #pragma unroll
    for (int ft = 0; ft < 4; ++ft) {
        bbv[ft] = b1w[ft*16 + col];
        wtv[ft] = W2w[ft*16 + col];
    }
    #pragma unroll
    for (int bt = 0; bt < 8; ++bt)
        #pragma unroll
        for (int r = 0; r < 4; ++r) {
            float part = 0.f;
            #pragma unroll
            for (int ft = 0; ft < 4; ++ft)
                part += tanhf(acc[bt][ft][r] + bbv[ft]) * wtv[ft];
            part += __shfl_xor(part, 1); part += __shfl_xor(part, 2);
            part += __shfl_xor(part, 4); part += __shfl_xor(part, 8);
            if (col == 0) s_red[wid][bt*16 + g*4 + r] = part;
        }
    __syncthreads();
    if (tid < 128) {
        float s = 0.f;
        #pragma unroll
        for (int wd = 0; wd < 8; ++wd) s += s_red[wd][tid];
        slater[w*NP + half*128 + tid] = s + b2[w];
    }
}

__device__ __forceinline__ float rf_f32(float x) {
    return __uint_as_float(__builtin_amdgcn_readfirstlane(__float_as_uint(x)));
}
__device__ __forceinline__ float rl_f32(float x, int lane) {
    return __uint_as_float(__builtin_amdgcn_readlane(__float_as_uint(x), lane));
}
template<int CTRL>
__device__ __forceinline__ unsigned dpp_u32(unsigned v) {
    return (unsigned)__builtin_amdgcn_update_dpp(0, (int)v, CTRL, 0xF, 0xF, true);
}

// Blocked (KB=8) partially-pivoted f32 LU, matrix register-resident.
// Byte-identical to the passing round-11..14 version.
__global__ __launch_bounds__(512, 1) void k_lu_blk(const float* __restrict__ A,
                                                   float* __restrict__ out)
{
    const int tid  = threadIdx.x;
    const int ln   = tid & 63;      // lane: row-in-quarter
    const int wv   = tid >> 6;      // wave id = 32-col slice (wave-uniform)
    const int cb   = wv * 32;       // col base

    __shared__ float s_panel[NP][KB+1];   // stride 9: conflict-free scalar access
    __shared__ float s_stage[2*KB][260];  // staged rows (full 256 cols + pad)
    __shared__ float s_U[KB][260];        // TRSM'd U block
    __shared__ int   s_src[NP];
    __shared__ int   s_p[KB];
    __shared__ int   s_uslot[KB];
    __shared__ float s_piv[NP];

    float a[4][32];                       // rows q*64+ln, cols cb..cb+31
    {
        const float4* Ap = reinterpret_cast<const float4*>(A);
        #pragma unroll
        for (int q = 0; q < 4; ++q)
            #pragma unroll
            for (int u = 0; u < 8; ++u) {
                float4 v = Ap[(q*64+ln)*64 + wv*8 + u];
                a[q][u*4+0]=v.x; a[q][u*4+1]=v.y; a[q][u*4+2]=v.z; a[q][u*4+3]=v.w;
            }
    }

    for (int pi = 0; pi < NP/KB; ++pi) {
        const int k0 = pi * KB;
        __syncthreads();                                  // B0

        // ---- STEP 1: stage panel cols + init s_src ----
        if (tid < 256) s_src[tid] = tid;
        if (wv == (k0 >> 5)) {                            // wave-uniform
            switch ((k0 & 31) >> 3) {
                case 0:
                    #pragma unroll
                    for (int q = 0; q < 4; ++q)
                        #pragma unroll
                        for (int c = 0; c < KB; ++c) s_panel[q*64+ln][c] = a[q][c];
                    break;
                case 1:
                    #pragma unroll
                    for (int q = 0; q < 4; ++q)
                        #pragma unroll
                        for (int c = 0; c < KB; ++c) s_panel[q*64+ln][c] = a[q][8+c];
                    break;
                case 2:
                    #pragma unroll
                    for (int q = 0; q < 4; ++q)
                        #pragma unroll
                        for (int c = 0; c < KB; ++c) s_panel[q*64+ln][c] = a[q][16+c];
                    break;
                default:
                    #pragma unroll
                    for (int q = 0; q < 4; ++q)
                        #pragma unroll
                        for (int c = 0; c < KB; ++c) s_panel[q*64+ln][c] = a[q][24+c];
                    break;
            }
        }
        __syncthreads();                                  // B1

        // ---- STEP 2: wave 0 factorizes the 256x8 panel (LDS-free core) ----
        if (tid < 64) {
            const int lane = tid;
            float pa[4][KB];
            int   lid[4];                  // logical position of slot q's row
            #pragma unroll
            for (int q = 0; q < 4; ++q) {
                lid[q] = q*64 + lane;
                #pragma unroll
                for (int c = 0; c < KB; ++c) pa[q][c] = s_panel[q*64+lane][c];
            }

            int pvt[KB];
            #pragma unroll
            for (int kk = 0; kk < KB; ++kk) {
                const int k = k0 + kk;
                // packed-key candidates: top-24 bits of |v| | (255 - lid)
                unsigned key = 0u;
                #pragma unroll
                for (int q = 0; q < 4; ++q) {
                    unsigned ab = __float_as_uint(pa[q][kk]) & 0x7FFFFFFFu;
                    unsigned kq = (ab & 0xFFFFFF00u) | (unsigned)(255 - lid[q]);
                    if (lid[q] >= k && kq > key) key = kq;
                }
                // 6-step DPP max-reduce -> lane 63 holds global max
                { unsigned t;
                  t = dpp_u32<0x111>(key); if (t > key) key = t;   // row_shr:1
                  t = dpp_u32<0x112>(key); if (t > key) key = t;   // row_shr:2
                  t = dpp_u32<0x114>(key); if (t > key) key = t;   // row_shr:4
                  t = dpp_u32<0x118>(key); if (t > key) key = t;   // row_shr:8
                  t = dpp_u32<0x142>(key); if (t > key) key = t;   // row_bcast:15
                  t = dpp_u32<0x143>(key); if (t > key) key = t;   // row_bcast:31
                }
                const unsigned gk = (unsigned)__builtin_amdgcn_readlane((int)key, 63);
                const int p = 255 - (int)(gk & 0xFFu);   // logical pivot row
                pvt[kk] = p;
                // physical holder of logical row p: (plane, pslot)
                int myslot = -1;
                #pragma unroll
                for (int q = 0; q < 4; ++q) if (lid[q] == p) myslot = q;
                unsigned long long bal = __ballot(myslot >= 0);
                const int plane = (int)__ffsll((long long)bal) - 1;
                const int pslot = __builtin_amdgcn_readlane(myslot, plane);
                // pivot-row broadcast (KB independent readlanes)
                float urow[KB];
                #pragma unroll
                for (int c = 0; c < KB; ++c) {
                    float t = (pslot==0) ? pa[0][c] : (pslot==1) ? pa[1][c]
                            : (pslot==2) ? pa[2][c] : pa[3][c];
                    urow[c] = rl_f32(t, plane);
                }
                // lazy swap of logical ids
                #pragma unroll
                for (int q = 0; q < 4; ++q) {
                    int lq = lid[q];
                    lid[q] = (lq == k) ? p : (lq == p) ? k : lq;
                }
                const float pv = urow[kk];
                if (lane == 0) s_piv[k] = (p != k) ? -pv : pv;
                const float rp = rf_f32(1.0f / pv);
                #pragma unroll
                for (int q = 0; q < 4; ++q)
                    if (lid[q] > k) pa[q][kk] *= rp;
                #pragma unroll
                for (int c = kk+1; c < KB; ++c) {
                    #pragma unroll
                    for (int q = 0; q < 4; ++q)
                        if (lid[q] > k) pa[q][c] = fmaf(-pa[q][kk], urow[c], pa[q][c]);
                }
            }
            // write back factored panel BY LOGICAL INDEX + pivots
            #pragma unroll
            for (int q = 0; q < 4; ++q)
                #pragma unroll
                for (int c = 0; c < KB; ++c) s_panel[lid[q]][c] = pa[q][c];
            if (lane == 0) {
                s_p[0]=pvt[0]; s_p[1]=pvt[1]; s_p[2]=pvt[2]; s_p[3]=pvt[3];
                s_p[4]=pvt[4]; s_p[5]=pvt[5]; s_p[6]=pvt[6]; s_p[7]=pvt[7];
            }
            // in-register swap simulation on 16 tracked positions
            int l8 = lane - 8;
            int psel = pvt[0];
            psel = (l8==1)?pvt[1]:psel; psel = (l8==2)?pvt[2]:psel;
            psel = (l8==3)?pvt[3]:psel; psel = (l8==4)?pvt[4]:psel;
            psel = (l8==5)?pvt[5]:psel; psel = (l8==6)?pvt[6]:psel;
            psel = (l8==7)?pvt[7]:psel;
            const int mypos = (lane < 8) ? (k0 + lane) : psel;
            int cur = mypos;
            #pragma unroll
            for (int s = 0; s < KB; ++s) {
                int cA = __builtin_amdgcn_readlane(cur, s);     // content at k0+s
                int cB = __builtin_amdgcn_readlane(cur, 8+s);   // content at pvt[s]
                int ks = k0 + s, ps = pvt[s];
                if (mypos == ks) cur = cB;
                else if (mypos == ps) cur = cA;
            }
            if (lane < 16) s_src[mypos] = cur;
            if (lane < 8) {
                int c = cur, slot = 8;
                slot = (pvt[0]==c)? 8:slot; slot = (pvt[1]==c)? 9:slot;
                slot = (pvt[2]==c)?10:slot; slot = (pvt[3]==c)?11:slot;
                slot = (pvt[4]==c)?12:slot; slot = (pvt[5]==c)?13:slot;
                slot = (pvt[6]==c)?14:slot; slot = (pvt[7]==c)?15:slot;
                if (c >= k0 && c < k0+KB) slot = c - k0;
                s_uslot[lane] = slot;
            }
        }
        __syncthreads();                                  // B2

        int pp[KB];
        #pragma unroll
        for (int s = 0; s < KB; ++s) pp[s] = s_p[s];

        // ---- STEP 3: stage affected rows (pre-swap content, by position) ----
        #pragma unroll
        for (int q = 0; q < 4; ++q) {
            const int iq = q*64 + ln;
            if (iq >= k0 && iq < k0+KB) {
                const int sl = iq - k0;
                #pragma unroll
                for (int u = 0; u < 8; ++u) {
                    float4 v; v.x=a[q][u*4+0]; v.y=a[q][u*4+1];
                    v.z=a[q][u*4+2]; v.w=a[q][u*4+3];
                    *reinterpret_cast<float4*>(&s_stage[sl][cb + u*4]) = v;
                }
            }
            #pragma unroll
            for (int s = 0; s < KB; ++s) {
                if (iq == pp[s]) {
                    #pragma unroll
                    for (int u = 0; u < 8; ++u) {
                        float4 v; v.x=a[q][u*4+0]; v.y=a[q][u*4+1];
                        v.z=a[q][u*4+2]; v.w=a[q][u*4+3];
                        *reinterpret_cast<float4*>(&s_stage[KB+s][cb + u*4]) = v;
                    }
                }
            }
        }
        __syncthreads();                                  // B3

        // ---- STEP 4a: apply row permutation from stage ----
        #pragma unroll
        for (int q = 0; q < 4; ++q) {
            const int iq = q*64 + ln;
            const int sr = s_src[iq];
            if (sr != iq) {
                int slot = 8;
                #pragma unroll
                for (int s = 0; s < KB; ++s) slot = (pp[s]==sr) ? KB+s : slot;
                if (sr >= k0 && sr < k0+KB) slot = sr - k0;
                #pragma unroll
                for (int u = 0; u < 8; ++u) {
                    float4 v = *reinterpret_cast<const float4*>(&s_stage[slot][cb + u*4]);
                    a[q][u*4+0]=v.x; a[q][u*4+1]=v.y; a[q][u*4+2]=v.z; a[q][u*4+3]=v.w;
                }
            }
        }
        // ---- STEP 4b: TRSM of U block, column-parallel (tid<256, col j=tid) ----
        if (tid < 256) {
            const int j = tid;
            int us[KB];
            #pragma unroll
            for (int m = 0; m < KB; ++m) us[m] = s_uslot[m];
            float uv[KB];
            #pragma unroll
            for (int m = 0; m < KB; ++m) {
                float v = s_stage[us[m]][j];
                #pragma unroll
                for (int s = 0; s < KB; ++s)
                    if (s < m) v = fmaf(-s_panel[k0+m][s], uv[s], v);
                uv[m] = v;
                s_U[m][j] = v;
            }
        }
        __syncthreads();                                  // B4

        // ---- STEP 5: rank-8 trailing update (live col slices only;
        //      dead rows in straddling q-blocks updated inertly) ----
        if (cb + 31 >= k0 + KB) {                         // wave-uniform
            float L0[4][KB];
            #pragma unroll
            for (int q = 0; q < 4; ++q)
                #pragma unroll
                for (int m = 0; m < KB; ++m) L0[q][m] = s_panel[q*64+ln][m];
            #pragma unroll
            for (int u4 = 0; u4 < 8; ++u4) {
                if (cb + u4*4 + 3 >= k0 + KB) {           // wave-uniform
                    #pragma unroll
                    for (int m = 0; m < KB; ++m) {
                        const float4 uv = *reinterpret_cast<const float4*>(&s_U[m][cb + u4*4]);
                        #pragma unroll
                        for (int q = 0; q < 4; ++q) {
                            if (q*64 + 63 >= k0 + KB) {   // wave-uniform: block has live rows
                                a[q][u4*4+0] = fmaf(-L0[q][m], uv.x, a[q][u4*4+0]);
                                a[q][u4*4+1] = fmaf(-L0[q][m], uv.y, a[q][u4*4+1]);
                                a[q][u4*4+2] = fmaf(-L0[q][m], uv.z, a[q][u4*4+2]);
                                a[q][u4*4+3] = fmaf(-L0[q][m], uv.w, a[q][u4*4+3]);
                            }
                        }
                    }
                }
            }
        }
    }
    __syncthreads();

    // ---- logdet = sum log|piv| (f64 accum), sign = parity of negatives ----
    if (tid < 64) {
        double ld = 0.0; int neg = 0;
        #pragma unroll
        for (int q = 0; q < 4; ++q) {
            float pv = s_piv[q*64 + tid];
            ld  += (double)logf(fabsf(pv));
            neg ^= (pv < 0.0f) ? 1 : 0;
        }
        #pragma unroll
        for (int off = 32; off; off >>= 1) {
            ld  += __shfl_xor(ld, off);
            neg ^= __shfl_xor(neg, off);
        }
        if (tid == 0) { out[0] = neg ? -1.0f : 1.0f; out[1] = (float)ld; }
    }
}

extern "C" void kernel_launch(void* const* d_in, const int* in_sizes, int n_in,
                              void* d_out, int out_size, void* d_ws, size_t ws_size,
                              hipStream_t stream)
{
    const float* x  = (const float*)d_in[0];
    const float* W0 = (const float*)d_in[1];
    const float* b0 = (const float*)d_in[2];
    const float* W1 = (const float*)d_in[3];
    const float* b1 = (const float*)d_in[4];
    const float* W2 = (const float*)d_in[5];
    const float* b2 = (const float*)d_in[6];
    float* out    = (float*)d_out;
    float* slater = (float*)d_ws;           // 256*256*4 = 256 KB scratch

    k_mlp_v3<<<512, 512, 0, stream>>>(x, W0, b0, W1, b1, W2, b2, slater);
    k_lu_blk<<<1, 512, 0, stream>>>(slater, out);
}